// Round 12
// baseline (249.408 us; speedup 1.0000x reference)
//
#include <hip/hip_runtime.h>

#define K_SEL 103
typedef unsigned long long ull_t;
typedef _Float16 f16x8 __attribute__((ext_vector_type(8)));
typedef _Float16 f16x4 __attribute__((ext_vector_type(4)));
typedef float f32x4 __attribute__((ext_vector_type(4)));

// ================= K12: fused (k2 select+MLP | k1 lin+W2th), B=512 ==========
// grid 768 = 3 blocks/CU x 256 CUs. blocks [0,512) select+MLP; [512,768) lin.
// R12 = R9 verbatim EXCEPT the MLP: kf[32] eliminated via on-the-fly sin/cos
// accumulation into 8 named scalars (peak regs ~50 -> ~20). R10/R11's
// vectorized-W1 attempts spilled (PMC: VGPR 40, scratch MB-scale) -- this
// goes the other way: lower pressure, same LDS-read count (scalar broadcast).
__global__ __launch_bounds__(512, 6) void k12(const float* __restrict__ pos,
                                              const float* __restrict__ qpos,
                                              const float* __restrict__ Bmat,
                                              const float* __restrict__ W1,
                                              const float* __restrict__ b1,
                                              _Float16* __restrict__ Hh,
                                              int* __restrict__ indg,
                                              float* __restrict__ invtot,
                                              const float* __restrict__ x,
                                              const float* __restrict__ W,
                                              const float* __restrict__ b,
                                              _Float16* __restrict__ xlh,
                                              const float* __restrict__ W2,
                                              const float* __restrict__ filt,
                                              _Float16* __restrict__ W2th) {
    __shared__ __align__(16) unsigned char smem[47392];
    const int tid = threadIdx.x;
    const int bid = blockIdx.x;
    const int lane = tid & 63;
    const int wid = tid >> 6;          // 0..7

    if (bid >= 512) {
        // ---------------- k1 path: 64 rows + W2th chunk --------------------
        const int bb = bid - 512;
        float* Wt = (float*)smem;                  // 64x65 (pad kills 64-way conflict)
        if (tid < 264) {
            int t = bb * 264 + tid;                // 256*264 = 67584 exactly
            int d = t & 31;
            int e = t >> 5;
            int c = e & 63;
            int j = e >> 6;
            float v = (j < 32) ? W2[(c * 32 + d) * 32 + j] : filt[c * 32 + d];
            W2th[d * 2112 + e] = (_Float16)v;
        }
        for (int t = tid; t < 4096; t += 512)
            Wt[(t & 63) * 65 + (t >> 6)] = W[t];
        __syncthreads();
        const int i = tid & 63;
        const int sub = tid >> 6;                  // 0..7
        const float bi = b[i];
        #pragma unroll
        for (int rr = 0; rr < 2; ++rr) {
            const int r0 = bb * 64 + rr * 32 + sub * 4;
            float acc0 = bi, acc1 = bi, acc2 = bi, acc3 = bi;
            const float* xr = x + (size_t)r0 * 64;
            #pragma unroll 4
            for (int jj = 0; jj < 16; ++jj) {
                float4 v0 = *(const float4*)(xr + 0 * 64 + jj * 4);
                float4 v1 = *(const float4*)(xr + 1 * 64 + jj * 4);
                float4 v2 = *(const float4*)(xr + 2 * 64 + jj * 4);
                float4 v3 = *(const float4*)(xr + 3 * 64 + jj * 4);
                float w0 = Wt[(jj * 4 + 0) * 65 + i];
                float w1 = Wt[(jj * 4 + 1) * 65 + i];
                float w2 = Wt[(jj * 4 + 2) * 65 + i];
                float w3 = Wt[(jj * 4 + 3) * 65 + i];
                acc0 += v0.x * w0 + v0.y * w1 + v0.z * w2 + v0.w * w3;
                acc1 += v1.x * w0 + v1.y * w1 + v1.z * w2 + v1.w * w3;
                acc2 += v2.x * w0 + v2.y * w1 + v2.z * w2 + v2.w * w3;
                acc3 += v3.x * w0 + v3.y * w1 + v3.z * w2 + v3.w * w3;
            }
            xlh[(size_t)(r0 + 0) * 64 + i] = (_Float16)acc0;
            xlh[(size_t)(r0 + 1) * 64 + i] = (_Float16)acc1;
            xlh[(size_t)(r0 + 2) * 64 + i] = (_Float16)acc2;
            xlh[(size_t)(r0 + 3) * 64 + i] = (_Float16)acc3;
        }
        return;
    }

    // ---------------- k2 path: select + MLP --------------------------------
    const int q = bid;
    unsigned* ebits   = (unsigned*)(smem);            // 8192 B
    unsigned* hist    = (unsigned*)(smem + 8192);     // 16384 B
    _Float16* Hs      = (_Float16*)(smem + 8192);     // 12288 B (alias hist)
    float2*   dpair   = (float2*)(smem + 24576);      // 16384 B (2048 float2)
    float*    W1t     = (float*)(smem + 40960);       // 33x32 f = 4224 B
    float*    b1s     = (float*)(smem + 45184);
    float*    Bm      = (float*)(smem + 45312);
    int*      sel_v   = (int*)(smem + 45440);         // 104
    float*    sel_e   = (float*)(smem + 45856);       // 104
    ull_t*    bnd     = (ull_t*)(smem + 46272);       // 128
    int*      counters= (int*)(smem + 47296);         // 2
    int*      info    = (int*)(smem + 47304);         // 2
    float*    wred    = (float*)(smem + 47312);       // 8
    float*    emax_s  = (float*)(smem + 47344);       // 1
    unsigned* wscan   = (unsigned*)(smem + 47348);    // 8

    // preload pos into regs (latency hides under LDS staging below)
    float2 p4[4];
    #pragma unroll
    for (int i = 0; i < 4; ++i) p4[i] = ((const float2*)pos)[tid + i * 512];
    const float qp0 = qpos[q * 2 + 0];
    const float qp1 = qpos[q * 2 + 1];

    for (int t = tid; t < 1024; t += 512)
        W1t[(t & 31) * 33 + (t >> 5)] = W1[t];        // transposed, stride 33
    if (tid < 32) { b1s[tid] = b1[tid]; Bm[tid] = Bmat[tid]; }
    if (tid < 2)  counters[tid] = 0;
    for (int t = tid; t < 1024; t += 512) ((uint4*)hist)[t] = make_uint4(0, 0, 0, 0);
    __syncthreads();

    float lmin = 1e30f;
    #pragma unroll
    for (int i = 0; i < 4; ++i) {
        const int v = tid + i * 512;
        float d0 = qp0 - p4[i].x;
        float d1 = qp1 - p4[i].y;
        d0 += 0.5f; d0 -= floorf(d0); d0 -= 0.5f;
        d1 += 0.5f; d1 -= floorf(d1); d1 -= 0.5f;
        float e = d0 * d0 + d1 * d1;
        ebits[v] = __float_as_uint(e);
        dpair[v] = make_float2(d0, d1);
        lmin = fminf(lmin, e);
        int bb2 = (int)(e * 8192.0f); bb2 = (bb2 > 4095) ? 4095 : bb2;
        atomicAdd(&hist[bb2], 1u);
    }
    #pragma unroll
    for (int off = 32; off > 0; off >>= 1)
        lmin = fminf(lmin, __shfl_xor(lmin, off, 64));
    if (lane == 0) wred[wid] = lmin;
    __syncthreads();
    float e_min = wred[0];
    #pragma unroll
    for (int w2 = 1; w2 < 8; ++w2) e_min = fminf(e_min, wred[w2]);

    // ---- hist scan: 8 bins/thread, vectorized read, bins kept in regs
    unsigned hb[8];
    {
        uint4 h0 = ((const uint4*)hist)[tid * 2];
        uint4 h1 = ((const uint4*)hist)[tid * 2 + 1];
        hb[0] = h0.x; hb[1] = h0.y; hb[2] = h0.z; hb[3] = h0.w;
        hb[4] = h1.x; hb[5] = h1.y; hb[6] = h1.z; hb[7] = h1.w;
    }
    unsigned lsum = 0;
    #pragma unroll
    for (int i = 0; i < 8; ++i) lsum += hb[i];
    unsigned vq = lsum;
    #pragma unroll
    for (int off = 1; off < 64; off <<= 1) {
        unsigned n = __shfl_up(vq, off, 64);
        if (lane >= off) vq += n;
    }
    if (lane == 63) wscan[wid] = vq;
    __syncthreads();
    unsigned base = 0;
    for (int w2 = 0; w2 < wid; ++w2) base += wscan[w2];
    unsigned cum = base + vq - lsum;
    #pragma unroll
    for (int i = 0; i < 8; ++i) {
        unsigned cnt = hb[i];
        if (cum <= 102u && 102u < cum + cnt) { info[0] = tid * 8 + i; info[1] = (int)cum; }
        cum += cnt;
    }
    __syncthreads();          // all hist reads done -> hist dead
    const int Bstar = info[0];
    const int L = info[1];
    const int need = K_SEL - L;

    {   // zero Hs (aliases dead hist)
        f16x8 z = {0, 0, 0, 0, 0, 0, 0, 0};
        for (int t = tid; t < 768; t += 512) ((f16x8*)Hs)[t] = z;
    }
    #pragma unroll
    for (int i = 0; i < 4; ++i) {
        const int v = tid + i * 512;
        unsigned bb2 = ebits[v];
        float e = __uint_as_float(bb2);
        int bin = (int)(e * 8192.0f); bin = (bin > 4095) ? 4095 : bin;
        // ---- ballot-compacted appends: one LDS atomic per wave ----
        bool tl = (bin < Bstar);
        ull_t ml = __ballot(tl);
        if (ml) {
            int ldr = (int)(__ffsll((long long)ml) - 1);
            int cnt = (int)__popcll(ml);
            int bs = 0;
            if (lane == ldr) bs = atomicAdd(&counters[0], cnt);
            bs = __shfl(bs, ldr, 64);
            if (tl) {
                int pos2 = bs + (int)__popcll(ml & ((1ull << lane) - 1ull));
                sel_v[pos2] = v; sel_e[pos2] = e;
            }
        }
        bool tb = (bin == Bstar);
        ull_t mb = __ballot(tb);
        if (mb) {
            int ldr = (int)(__ffsll((long long)mb) - 1);
            int cnt = (int)__popcll(mb);
            int bs = 0;
            if (lane == ldr) bs = atomicAdd(&counters[1], cnt);
            bs = __shfl(bs, ldr, 64);
            if (tb) {
                int pos2 = bs + (int)__popcll(mb & ((1ull << lane) - 1ull));
                if (pos2 < 128) bnd[pos2] = (((ull_t)bb2) << 32) | (unsigned)v;
            }
        }
    }
    __syncthreads();
    {   // parallel rank-select over boundary items (keys unique)
        int nb = counters[1]; if (nb > 128) nb = 128;
        if (tid < nb) {
            ull_t my = bnd[tid];
            int rank = 0;
            for (int i = 0; i < nb; ++i) rank += (bnd[i] < my);
            if (rank < need) {
                sel_v[L + rank] = (int)(unsigned)(my & 0xffffffffull);
                sel_e[L + rank] = __uint_as_float((unsigned)(my >> 32));
            }
            if (rank == need - 1)
                emax_s[0] = __uint_as_float((unsigned)(my >> 32));
        }
    }
    __syncthreads();

    const float denom = (emax_s[0] - e_min) + 1e-8f;
    float w = 0.0f;
    if (tid < K_SEL) {
        w = __expf(-(sel_e[tid] - e_min) / denom);
        sel_e[tid] = w;
    }
    float sw = w;
    #pragma unroll
    for (int off = 32; off > 0; off >>= 1)
        sw += __shfl_xor(sw, off, 64);
    if (lane == 0) wred[wid] = sw;
    __syncthreads();
    if (tid == 0) {
        float tot = 0.0f;
        #pragma unroll
        for (int w2 = 0; w2 < 8; ++w2) tot += wred[w2];
        invtot[q] = 1.0f / tot;
    }

    // ---- MLP with unnormalized w: 4 threads per k (8 outputs each) ----
    // R12: no kf[32] -- per-f on-the-fly sin/cos FMA'd into 8 named
    // accumulators. Peak live regs ~20 (was ~50). Scalar stride-33 LDS
    // reads: io in {0,8,16,24} -> 4-addr broadcast, 4 distinct banks.
    if (tid < 4 * K_SEL) {
        const int k = tid >> 2;
        const int io = (tid & 3) * 8;
        const int sw5 = ((tid & 3) & 1) << 5;      // Hs col-XOR (bank spread)
        const int v = sel_v[k];
        const float wk = sel_e[k];
        float2 dp = dpair[v];                      // cached (d0,d1)
        const float d0 = dp.x;
        const float d1 = dp.y;
        float pre0 = b1s[io + 0], pre1 = b1s[io + 1];
        float pre2 = b1s[io + 2], pre3 = b1s[io + 3];
        float pre4 = b1s[io + 4], pre5 = b1s[io + 5];
        float pre6 = b1s[io + 6], pre7 = b1s[io + 7];
        #pragma unroll
        for (int f = 0; f < 16; ++f) {
            float t = d0 * Bm[f] + d1 * Bm[16 + f];   // revolutions
            float r = t - rintf(t);
            float s = __builtin_amdgcn_sinf(r);
            float c = __builtin_amdgcn_cosf(r);
            const float* wsr = &W1t[f * 33 + io];          // sin row
            const float* wcr = &W1t[(16 + f) * 33 + io];   // cos row
            pre0 += s * wsr[0] + c * wcr[0];
            pre1 += s * wsr[1] + c * wcr[1];
            pre2 += s * wsr[2] + c * wcr[2];
            pre3 += s * wsr[3] + c * wcr[3];
            pre4 += s * wsr[4] + c * wcr[4];
            pre5 += s * wsr[5] + c * wcr[5];
            pre6 += s * wsr[6] + c * wcr[6];
            pre7 += s * wsr[7] + c * wcr[7];
        }
        const float k2s = 0.70710678118654752f;
        const int hcol = k ^ sw5;
        Hs[(io + 0) * 128 + hcol] = (_Float16)(0.5f * pre0 * (1.0f + erff(pre0 * k2s)) * wk);
        Hs[(io + 1) * 128 + hcol] = (_Float16)(0.5f * pre1 * (1.0f + erff(pre1 * k2s)) * wk);
        Hs[(io + 2) * 128 + hcol] = (_Float16)(0.5f * pre2 * (1.0f + erff(pre2 * k2s)) * wk);
        Hs[(io + 3) * 128 + hcol] = (_Float16)(0.5f * pre3 * (1.0f + erff(pre3 * k2s)) * wk);
        Hs[(io + 4) * 128 + hcol] = (_Float16)(0.5f * pre4 * (1.0f + erff(pre4 * k2s)) * wk);
        Hs[(io + 5) * 128 + hcol] = (_Float16)(0.5f * pre5 * (1.0f + erff(pre5 * k2s)) * wk);
        Hs[(io + 6) * 128 + hcol] = (_Float16)(0.5f * pre6 * (1.0f + erff(pre6 * k2s)) * wk);
        Hs[(io + 7) * 128 + hcol] = (_Float16)(0.5f * pre7 * (1.0f + erff(pre7 * k2s)) * wk);
        if (io == 0) {
            Hs[32 * 128 + k] = (_Float16)wk;   // i=32 row: no swizzle
            indg[q * 128 + k] = v;
            if (k < 128 - K_SEL) indg[q * 128 + K_SEL + k] = v;  // wrap pad
        }
    }
    __syncthreads();
    {
        _Float16* hq = Hh + (size_t)q * 6144;
        for (int t = tid; t < 768; t += 512)
            ((f16x8*)hq)[t] = ((const f16x8*)Hs)[t];
    }
}

// ---------------- K3q: ONE block per q (512 thr, 8 waves), 8 bt ------------
// grid 512 = 2 blocks/CU. R9 structure verbatim: 2-deep pipelined gather,
// int4-direct indices, GEMM2 W2th prefetch, all R6/R7 LDS layouts.
__global__ __launch_bounds__(512, 4) void k3_main(const _Float16* __restrict__ xlh,
                                                  const _Float16* __restrict__ Hh,
                                                  const int* __restrict__ indg,
                                                  const _Float16* __restrict__ W2th,
                                                  const float* __restrict__ bias,
                                                  const float* __restrict__ invtot,
                                                  float* __restrict__ out) {
    const int q = blockIdx.x;
    const int tid = threadIdx.x;
    const int lane = tid & 63;
    const int wid = tid >> 6;          // 0..7
    const int h   = wid >> 2;          // bt-half within pass (0/1)
    const int cq  = wid & 3;           // channel quarter
    const int n0 = lane & 15;
    const int quad = lane >> 4;

    __shared__ __align__(16) unsigned char smem[68992];
    _Float16* Xg  = (_Float16*)smem;                 // 2 x 8768 halfs = 35072 B
    _Float16* Zh8 = (_Float16*)(smem + 35072);       // 8 x 2120 halfs = 33920 B
    float* red    = (float*)smem;                    // aliases dead Xg (2048 f)

    // gather mapping: thread -> (h, kblk, oct); 4 consecutive k per thread
    const int m_oct = tid & 7;               // channel octet
    const int m_kb  = (tid >> 3) & 31;       // k-block of 4
    const int m_h   = tid >> 8;              // bt-half of this load
    const int m_k0  = m_kb * 4;
    const int m_base = m_h * 8768 + m_oct * 1096 + m_k0;  // + 136*jj per row

    // direct register index load (padded indg, wrap entries pre-written)
    const int4 ind4 = *(const int4*)(indg + q * 128 + m_k0);
    int indr[4] = {ind4.x, ind4.y, ind4.z, ind4.w};

    const _Float16* hq = Hh + (size_t)q * 6144;
    f16x8 afr[4][3];
    #pragma unroll
    for (int ks = 0; ks < 4; ++ks)
        #pragma unroll
        for (int r = 0; r < 3; ++r)
            afr[ks][r] = *(const f16x8*)(hq + (r * 16 + n0) * 128 +
                                         ((ks * 32 + quad * 8) ^ ((n0 >> 3) << 5)));
    const float it = invtot[q];
    const int e0f = wid * 32 + quad * 8;             // flat e for W2th (global)
    f16x8 pf0 = *(const f16x8*)(W2th + (size_t)(0 * 16 + n0) * 2112 + e0f);
    f16x8 pf1 = *(const f16x8*)(W2th + (size_t)(1 * 16 + n0) * 2112 + e0f);

    // ---- 2-deep pipelined gather: v_stg = pass p data (staged now),
    //      v_nxt = pass p+1 data (regs), v_pf = pass p+2 (issued in pass p)
    f16x8 v_stg[4], v_nxt[4];
    #pragma unroll
    for (int i = 0; i < 4; ++i)
        v_stg[i] = *(const f16x8*)(xlh + ((size_t)(0 + m_h) * 2048 + indr[i]) * 64 + m_oct * 8);
    #pragma unroll
    for (int i = 0; i < 4; ++i)
        v_nxt[i] = *(const f16x8*)(xlh + ((size_t)(2 + m_h) * 2048 + indr[i]) * 64 + m_oct * 8);
    #pragma unroll
    for (int jj = 0; jj < 8; ++jj) {
        f16x4 pk = {v_stg[0][jj], v_stg[1][jj], v_stg[2][jj], v_stg[3][jj]};
        *(f16x4*)(&Xg[m_base + 136 * jj]) = pk;
    }
    __syncthreads();

    const int cA = cq * 16 + n0;
    const int cswz = h * 8768 + cA * 136 + ((cA >> 3) << 3);

    #pragma unroll
    for (int p = 0; p < 4; ++p) {
        f16x8 v_pf[4];
        if (p < 2) {      // issue pass p+2 loads now (2 passes of cover)
            #pragma unroll
            for (int i = 0; i < 4; ++i)
                v_pf[i] = *(const f16x8*)(xlh + ((size_t)(2 * (p + 2) + m_h) * 2048 + indr[i]) * 64 + m_oct * 8);
        }
        f32x4 Dz[3];
        #pragma unroll
        for (int r = 0; r < 3; ++r) Dz[r] = (f32x4){0.f, 0.f, 0.f, 0.f};
        #pragma unroll
        for (int ks = 0; ks < 4; ++ks) {
            f16x8 bfr = *(const f16x8*)(&Xg[cswz + ks * 32 + quad * 8]);
            #pragma unroll
            for (int r = 0; r < 3; ++r)
                Dz[r] = __builtin_amdgcn_mfma_f32_16x16x32_f16(afr[ks][r], bfr, Dz[r], 0, 0, 0);
        }
        __syncthreads();          // Xg reads done
        const int bt = 2 * p + h;
        #pragma unroll
        for (int r = 0; r < 3; ++r)
            #pragma unroll
            for (int reg = 0; reg < 4; ++reg) {
                int j = r * 16 + quad * 4 + reg;     // (j>>2)&3 == quad
                if (j < 33) Zh8[bt * 2120 + j * 64 + (cA ^ (quad << 4))] = (_Float16)Dz[r][reg];
            }
        if (p < 3) {
            #pragma unroll
            for (int jj = 0; jj < 8; ++jj) {
                f16x4 pk = {v_nxt[0][jj], v_nxt[1][jj], v_nxt[2][jj], v_nxt[3][jj]};
                *(f16x4*)(&Xg[m_base + 136 * jj]) = pk;
            }
            __syncthreads();
            #pragma unroll
            for (int i = 0; i < 4; ++i) v_nxt[i] = v_pf[i];   // rotate regs
        }
    }
    __syncthreads();              // all Zh8 writes visible

    // ---- GEMM2: one M=8 pass, s == wid (mod 8), s in [0,66) ---------------
    // Zh8 phys col = logical ^ (((j>>2)&3)<<4), j = s>>1 (matches write side)
    f32x4 D2[2][2];
    #pragma unroll
    for (int pp = 0; pp < 2; ++pp)
        #pragma unroll
        for (int dt = 0; dt < 2; ++dt) D2[pp][dt] = (f32x4){0.f, 0.f, 0.f, 0.f};
    {
        const int s = wid;
        const int ja = s >> 1;
        const int phys = (((s & 1) << 5) + quad * 8) ^ (((s >> 3) & 3) << 4);
        f16x8 a2 = {0, 0, 0, 0, 0, 0, 0, 0};
        if (n0 < 8) a2 = *(const f16x8*)(&Zh8[n0 * 2120 + ja * 64 + phys]);
        D2[0][0] = __builtin_amdgcn_mfma_f32_16x16x32_f16(a2, pf0, D2[0][0], 0, 0, 0);
        D2[0][1] = __builtin_amdgcn_mfma_f32_16x16x32_f16(a2, pf1, D2[0][1], 0, 0, 0);
    }
    // software-pipelined: cur regs hold s-iteration fragments, prefetch s+8
    f16x8 c0, c1;
    {
        const int s1 = wid + 8;
        const int e1 = s1 * 32 + quad * 8;
        c0 = *(const f16x8*)(W2th + (size_t)(0 * 16 + n0) * 2112 + e1);
        c1 = *(const f16x8*)(W2th + (size_t)(1 * 16 + n0) * 2112 + e1);
    }
    int pp = 1;
    for (int s = wid + 8; s < 66; s += 8) {
        const int sn = s + 8;
        f16x8 nx0, nx1;
        if (sn < 66) {
            const int en = sn * 32 + quad * 8;
            nx0 = *(const f16x8*)(W2th + (size_t)(0 * 16 + n0) * 2112 + en);
            nx1 = *(const f16x8*)(W2th + (size_t)(1 * 16 + n0) * 2112 + en);
        }
        const int ja = s >> 1;
        const int phys = (((s & 1) << 5) + quad * 8) ^ (((s >> 3) & 3) << 4);
        f16x8 a2 = {0, 0, 0, 0, 0, 0, 0, 0};
        if (n0 < 8) a2 = *(const f16x8*)(&Zh8[n0 * 2120 + ja * 64 + phys]);
        D2[pp][0] = __builtin_amdgcn_mfma_f32_16x16x32_f16(a2, c0, D2[pp][0], 0, 0, 0);
        D2[pp][1] = __builtin_amdgcn_mfma_f32_16x16x32_f16(a2, c1, D2[pp][1], 0, 0, 0);
        c0 = nx0; c1 = nx1;
        pp ^= 1;
    }
    #pragma unroll
    for (int dt = 0; dt < 2; ++dt)
        D2[0][dt] = D2[0][dt] + D2[1][dt];

    // D rows: bt = quad*4 + reg -> quads 0,1 hold bt 0..7
    if (quad < 2) {
        #pragma unroll
        for (int dt = 0; dt < 2; ++dt)
            #pragma unroll
            for (int reg = 0; reg < 4; ++reg)
                red[((wid * 2 + dt) * 8 + quad * 4 + reg) * 16 + n0] = D2[0][dt][reg];
    }
    __syncthreads();
    if (tid < 256) {
        const int bt = tid >> 5;
        const int d = tid & 31;
        const int dt = d >> 4;
        const int dn = d & 15;
        float s = 0.0f;
        #pragma unroll
        for (int w2 = 0; w2 < 8; ++w2)
            s += red[((w2 * 2 + dt) * 8 + bt) * 16 + dn];
        out[((size_t)bt * 512 + q) * 32 + d] = bias[d] + it * s;
    }
}

// ---------------------------------------------------------------------------
extern "C" void kernel_launch(void* const* d_in, const int* in_sizes, int n_in,
                              void* d_out, int out_size, void* d_ws, size_t ws_size,
                              hipStream_t stream) {
    const float* x     = (const float*)d_in[0];   // (2,4,2048,64)
    const float* pos   = (const float*)d_in[1];   // (2048,2)
    const float* qpos  = (const float*)d_in[2];   // (512,2)
    const float* W_lin = (const float*)d_in[3];   // (64,64)
    const float* b_lin = (const float*)d_in[4];   // (64)
    const float* Bmat  = (const float*)d_in[5];   // (2,16)
    const float* W1    = (const float*)d_in[6];   // (32,32)
    const float* b1    = (const float*)d_in[7];   // (32)
    const float* W2    = (const float*)d_in[8];   // (2048,32)
    const float* filt  = (const float*)d_in[9];   // (2048)
    const float* bias  = (const float*)d_in[10];  // (32)
    float* out = (float*)d_out;

    float* ws = (float*)d_ws;
    _Float16* xlh    = (_Float16*)ws;               // 1048576 halfs
    _Float16* Hh     = (_Float16*)(ws + 524288);    // 512*6144 halfs
    int*      indg   = (int*)(ws + 2097152);        // 512*128 ints (padded)
    _Float16* W2th   = (_Float16*)(ws + 2162688);   // 32*2112 halfs
    float*    invtot = ws + 2196480;                // 512 floats

    k12<<<768, 512, 0, stream>>>(pos, qpos, Bmat, W1, b1, Hh, indg, invtot,
                                 x, W_lin, b_lin, xlh, W2, filt, W2th);
    k3_main<<<512, 512, 0, stream>>>(xlh, Hh, indg, W2th, bias, invtot, out);
}

// Round 13
// 107.874 us; speedup vs baseline: 2.3120x; 2.3120x over previous
//
#include <hip/hip_runtime.h>

#define K_SEL 103
typedef unsigned long long ull_t;
typedef _Float16 f16x8 __attribute__((ext_vector_type(8)));
typedef _Float16 f16x4 __attribute__((ext_vector_type(4)));
typedef float f32x4 __attribute__((ext_vector_type(4)));

// ================= K12: fused (k2 select+MLP | k1 lin+W2th), B=512 ==========
// grid 768 = 3 blocks/CU x 256 CUs. blocks [0,512) select+MLP; [512,768) lin.
// R13 = R9 verbatim (session best, 108.3 us). The MLP inner loop is
// CODEGEN-FRAGILE: R10 (acc[4] array), R11 (named float2 pairs), R12
// (on-the-fly sin/cos) ALL triggered VGPR-40 + MB-scale scratch (PMC:
// WRITE 208-545 MB). Only this exact kf[32] + scalar stride-33 formulation
// compiles spill-free. DO NOT restructure the MLP without disasm evidence.
__global__ __launch_bounds__(512, 6) void k12(const float* __restrict__ pos,
                                              const float* __restrict__ qpos,
                                              const float* __restrict__ Bmat,
                                              const float* __restrict__ W1,
                                              const float* __restrict__ b1,
                                              _Float16* __restrict__ Hh,
                                              int* __restrict__ indg,
                                              float* __restrict__ invtot,
                                              const float* __restrict__ x,
                                              const float* __restrict__ W,
                                              const float* __restrict__ b,
                                              _Float16* __restrict__ xlh,
                                              const float* __restrict__ W2,
                                              const float* __restrict__ filt,
                                              _Float16* __restrict__ W2th) {
    __shared__ __align__(16) unsigned char smem[47392];
    const int tid = threadIdx.x;
    const int bid = blockIdx.x;
    const int lane = tid & 63;
    const int wid = tid >> 6;          // 0..7

    if (bid >= 512) {
        // ---------------- k1 path: 64 rows + W2th chunk --------------------
        const int bb = bid - 512;
        float* Wt = (float*)smem;                  // 64x65 (pad kills 64-way conflict)
        if (tid < 264) {
            int t = bb * 264 + tid;                // 256*264 = 67584 exactly
            int d = t & 31;
            int e = t >> 5;
            int c = e & 63;
            int j = e >> 6;
            float v = (j < 32) ? W2[(c * 32 + d) * 32 + j] : filt[c * 32 + d];
            W2th[d * 2112 + e] = (_Float16)v;
        }
        for (int t = tid; t < 4096; t += 512)
            Wt[(t & 63) * 65 + (t >> 6)] = W[t];
        __syncthreads();
        const int i = tid & 63;
        const int sub = tid >> 6;                  // 0..7
        const float bi = b[i];
        #pragma unroll
        for (int rr = 0; rr < 2; ++rr) {
            const int r0 = bb * 64 + rr * 32 + sub * 4;
            float acc0 = bi, acc1 = bi, acc2 = bi, acc3 = bi;
            const float* xr = x + (size_t)r0 * 64;
            #pragma unroll 4
            for (int jj = 0; jj < 16; ++jj) {
                float4 v0 = *(const float4*)(xr + 0 * 64 + jj * 4);
                float4 v1 = *(const float4*)(xr + 1 * 64 + jj * 4);
                float4 v2 = *(const float4*)(xr + 2 * 64 + jj * 4);
                float4 v3 = *(const float4*)(xr + 3 * 64 + jj * 4);
                float w0 = Wt[(jj * 4 + 0) * 65 + i];
                float w1 = Wt[(jj * 4 + 1) * 65 + i];
                float w2 = Wt[(jj * 4 + 2) * 65 + i];
                float w3 = Wt[(jj * 4 + 3) * 65 + i];
                acc0 += v0.x * w0 + v0.y * w1 + v0.z * w2 + v0.w * w3;
                acc1 += v1.x * w0 + v1.y * w1 + v1.z * w2 + v1.w * w3;
                acc2 += v2.x * w0 + v2.y * w1 + v2.z * w2 + v2.w * w3;
                acc3 += v3.x * w0 + v3.y * w1 + v3.z * w2 + v3.w * w3;
            }
            xlh[(size_t)(r0 + 0) * 64 + i] = (_Float16)acc0;
            xlh[(size_t)(r0 + 1) * 64 + i] = (_Float16)acc1;
            xlh[(size_t)(r0 + 2) * 64 + i] = (_Float16)acc2;
            xlh[(size_t)(r0 + 3) * 64 + i] = (_Float16)acc3;
        }
        return;
    }

    // ---------------- k2 path: select + MLP --------------------------------
    const int q = bid;
    unsigned* ebits   = (unsigned*)(smem);            // 8192 B
    unsigned* hist    = (unsigned*)(smem + 8192);     // 16384 B
    _Float16* Hs      = (_Float16*)(smem + 8192);     // 12288 B (alias hist)
    float2*   dpair   = (float2*)(smem + 24576);      // 16384 B (2048 float2)
    float*    W1t     = (float*)(smem + 40960);       // 33x32 f = 4224 B
    float*    b1s     = (float*)(smem + 45184);
    float*    Bm      = (float*)(smem + 45312);
    int*      sel_v   = (int*)(smem + 45440);         // 104
    float*    sel_e   = (float*)(smem + 45856);       // 104
    ull_t*    bnd     = (ull_t*)(smem + 46272);       // 128
    int*      counters= (int*)(smem + 47296);         // 2
    int*      info    = (int*)(smem + 47304);         // 2
    float*    wred    = (float*)(smem + 47312);       // 8
    float*    emax_s  = (float*)(smem + 47344);       // 1
    unsigned* wscan   = (unsigned*)(smem + 47348);    // 8

    // preload pos into regs (latency hides under LDS staging below)
    float2 p4[4];
    #pragma unroll
    for (int i = 0; i < 4; ++i) p4[i] = ((const float2*)pos)[tid + i * 512];
    const float qp0 = qpos[q * 2 + 0];
    const float qp1 = qpos[q * 2 + 1];

    for (int t = tid; t < 1024; t += 512)
        W1t[(t & 31) * 33 + (t >> 5)] = W1[t];        // transposed, stride 33
    if (tid < 32) { b1s[tid] = b1[tid]; Bm[tid] = Bmat[tid]; }
    if (tid < 2)  counters[tid] = 0;
    for (int t = tid; t < 1024; t += 512) ((uint4*)hist)[t] = make_uint4(0, 0, 0, 0);
    __syncthreads();

    float lmin = 1e30f;
    #pragma unroll
    for (int i = 0; i < 4; ++i) {
        const int v = tid + i * 512;
        float d0 = qp0 - p4[i].x;
        float d1 = qp1 - p4[i].y;
        d0 += 0.5f; d0 -= floorf(d0); d0 -= 0.5f;
        d1 += 0.5f; d1 -= floorf(d1); d1 -= 0.5f;
        float e = d0 * d0 + d1 * d1;
        ebits[v] = __float_as_uint(e);
        dpair[v] = make_float2(d0, d1);
        lmin = fminf(lmin, e);
        int bb2 = (int)(e * 8192.0f); bb2 = (bb2 > 4095) ? 4095 : bb2;
        atomicAdd(&hist[bb2], 1u);
    }
    #pragma unroll
    for (int off = 32; off > 0; off >>= 1)
        lmin = fminf(lmin, __shfl_xor(lmin, off, 64));
    if (lane == 0) wred[wid] = lmin;
    __syncthreads();
    float e_min = wred[0];
    #pragma unroll
    for (int w2 = 1; w2 < 8; ++w2) e_min = fminf(e_min, wred[w2]);

    // ---- hist scan: 8 bins/thread, vectorized read, bins kept in regs
    unsigned hb[8];
    {
        uint4 h0 = ((const uint4*)hist)[tid * 2];
        uint4 h1 = ((const uint4*)hist)[tid * 2 + 1];
        hb[0] = h0.x; hb[1] = h0.y; hb[2] = h0.z; hb[3] = h0.w;
        hb[4] = h1.x; hb[5] = h1.y; hb[6] = h1.z; hb[7] = h1.w;
    }
    unsigned lsum = 0;
    #pragma unroll
    for (int i = 0; i < 8; ++i) lsum += hb[i];
    unsigned vq = lsum;
    #pragma unroll
    for (int off = 1; off < 64; off <<= 1) {
        unsigned n = __shfl_up(vq, off, 64);
        if (lane >= off) vq += n;
    }
    if (lane == 63) wscan[wid] = vq;
    __syncthreads();
    unsigned base = 0;
    for (int w2 = 0; w2 < wid; ++w2) base += wscan[w2];
    unsigned cum = base + vq - lsum;
    #pragma unroll
    for (int i = 0; i < 8; ++i) {
        unsigned cnt = hb[i];
        if (cum <= 102u && 102u < cum + cnt) { info[0] = tid * 8 + i; info[1] = (int)cum; }
        cum += cnt;
    }
    __syncthreads();          // all hist reads done -> hist dead
    const int Bstar = info[0];
    const int L = info[1];
    const int need = K_SEL - L;

    {   // zero Hs (aliases dead hist)
        f16x8 z = {0, 0, 0, 0, 0, 0, 0, 0};
        for (int t = tid; t < 768; t += 512) ((f16x8*)Hs)[t] = z;
    }
    #pragma unroll
    for (int i = 0; i < 4; ++i) {
        const int v = tid + i * 512;
        unsigned bb2 = ebits[v];
        float e = __uint_as_float(bb2);
        int bin = (int)(e * 8192.0f); bin = (bin > 4095) ? 4095 : bin;
        // ---- ballot-compacted appends: one LDS atomic per wave ----
        bool tl = (bin < Bstar);
        ull_t ml = __ballot(tl);
        if (ml) {
            int ldr = (int)(__ffsll((long long)ml) - 1);
            int cnt = (int)__popcll(ml);
            int bs = 0;
            if (lane == ldr) bs = atomicAdd(&counters[0], cnt);
            bs = __shfl(bs, ldr, 64);
            if (tl) {
                int pos2 = bs + (int)__popcll(ml & ((1ull << lane) - 1ull));
                sel_v[pos2] = v; sel_e[pos2] = e;
            }
        }
        bool tb = (bin == Bstar);
        ull_t mb = __ballot(tb);
        if (mb) {
            int ldr = (int)(__ffsll((long long)mb) - 1);
            int cnt = (int)__popcll(mb);
            int bs = 0;
            if (lane == ldr) bs = atomicAdd(&counters[1], cnt);
            bs = __shfl(bs, ldr, 64);
            if (tb) {
                int pos2 = bs + (int)__popcll(mb & ((1ull << lane) - 1ull));
                if (pos2 < 128) bnd[pos2] = (((ull_t)bb2) << 32) | (unsigned)v;
            }
        }
    }
    __syncthreads();
    {   // parallel rank-select over boundary items (keys unique)
        int nb = counters[1]; if (nb > 128) nb = 128;
        if (tid < nb) {
            ull_t my = bnd[tid];
            int rank = 0;
            for (int i = 0; i < nb; ++i) rank += (bnd[i] < my);
            if (rank < need) {
                sel_v[L + rank] = (int)(unsigned)(my & 0xffffffffull);
                sel_e[L + rank] = __uint_as_float((unsigned)(my >> 32));
            }
            if (rank == need - 1)
                emax_s[0] = __uint_as_float((unsigned)(my >> 32));
        }
    }
    __syncthreads();

    const float denom = (emax_s[0] - e_min) + 1e-8f;
    float w = 0.0f;
    if (tid < K_SEL) {
        w = __expf(-(sel_e[tid] - e_min) / denom);
        sel_e[tid] = w;
    }
    float sw = w;
    #pragma unroll
    for (int off = 32; off > 0; off >>= 1)
        sw += __shfl_xor(sw, off, 64);
    if (lane == 0) wred[wid] = sw;
    __syncthreads();
    if (tid == 0) {
        float tot = 0.0f;
        #pragma unroll
        for (int w2 = 0; w2 < 8; ++w2) tot += wred[w2];
        invtot[q] = 1.0f / tot;
    }

    // ---- MLP with unnormalized w: 4 threads per k (8 outputs each)
    if (tid < 4 * K_SEL) {
        const int k = tid >> 2;
        const int io = (tid & 3) * 8;
        const int sw5 = ((tid & 3) & 1) << 5;      // Hs col-XOR (bank spread)
        const int v = sel_v[k];
        const float wk = sel_e[k];
        float2 dp = dpair[v];                      // cached (d0,d1), bit-exact
        const float d0 = dp.x;
        const float d1 = dp.y;
        float kf[32];
        #pragma unroll
        for (int f = 0; f < 16; ++f) {
            float t = d0 * Bm[f] + d1 * Bm[16 + f];   // revolutions
            float r = t - rintf(t);
            kf[f]      = __builtin_amdgcn_sinf(r);
            kf[16 + f] = __builtin_amdgcn_cosf(r);
        }
        #pragma unroll
        for (int i = io; i < io + 8; ++i) {
            float pre = b1s[i];
            #pragma unroll
            for (int jf = 0; jf < 32; ++jf) pre += kf[jf] * W1t[jf * 33 + i];
            float g = 0.5f * pre * (1.0f + erff(pre * 0.70710678118654752f));
            Hs[i * 128 + (k ^ sw5)] = (_Float16)(g * wk);
        }
        if (io == 0) {
            Hs[32 * 128 + k] = (_Float16)wk;   // i=32 row: no swizzle
            indg[q * 128 + k] = v;
            if (k < 128 - K_SEL) indg[q * 128 + K_SEL + k] = v;  // wrap pad
        }
    }
    __syncthreads();
    {
        _Float16* hq = Hh + (size_t)q * 6144;
        for (int t = tid; t < 768; t += 512)
            ((f16x8*)hq)[t] = ((const f16x8*)Hs)[t];
    }
}

// ---------------- K3q: ONE block per q (512 thr, 8 waves), 8 bt ------------
// grid 512 = 2 blocks/CU. R9 structure verbatim: 2-deep pipelined gather,
// int4-direct indices, GEMM2 W2th prefetch, all R6/R7 LDS layouts.
__global__ __launch_bounds__(512, 4) void k3_main(const _Float16* __restrict__ xlh,
                                                  const _Float16* __restrict__ Hh,
                                                  const int* __restrict__ indg,
                                                  const _Float16* __restrict__ W2th,
                                                  const float* __restrict__ bias,
                                                  const float* __restrict__ invtot,
                                                  float* __restrict__ out) {
    const int q = blockIdx.x;
    const int tid = threadIdx.x;
    const int lane = tid & 63;
    const int wid = tid >> 6;          // 0..7
    const int h   = wid >> 2;          // bt-half within pass (0/1)
    const int cq  = wid & 3;           // channel quarter
    const int n0 = lane & 15;
    const int quad = lane >> 4;

    __shared__ __align__(16) unsigned char smem[68992];
    _Float16* Xg  = (_Float16*)smem;                 // 2 x 8768 halfs = 35072 B
    _Float16* Zh8 = (_Float16*)(smem + 35072);       // 8 x 2120 halfs = 33920 B
    float* red    = (float*)smem;                    // aliases dead Xg (2048 f)

    // gather mapping: thread -> (h, kblk, oct); 4 consecutive k per thread
    const int m_oct = tid & 7;               // channel octet
    const int m_kb  = (tid >> 3) & 31;       // k-block of 4
    const int m_h   = tid >> 8;              // bt-half of this load
    const int m_k0  = m_kb * 4;
    const int m_base = m_h * 8768 + m_oct * 1096 + m_k0;  // + 136*jj per row

    // direct register index load (padded indg, wrap entries pre-written)
    const int4 ind4 = *(const int4*)(indg + q * 128 + m_k0);
    int indr[4] = {ind4.x, ind4.y, ind4.z, ind4.w};

    const _Float16* hq = Hh + (size_t)q * 6144;
    f16x8 afr[4][3];
    #pragma unroll
    for (int ks = 0; ks < 4; ++ks)
        #pragma unroll
        for (int r = 0; r < 3; ++r)
            afr[ks][r] = *(const f16x8*)(hq + (r * 16 + n0) * 128 +
                                         ((ks * 32 + quad * 8) ^ ((n0 >> 3) << 5)));
    const float it = invtot[q];
    const int e0f = wid * 32 + quad * 8;             // flat e for W2th (global)
    f16x8 pf0 = *(const f16x8*)(W2th + (size_t)(0 * 16 + n0) * 2112 + e0f);
    f16x8 pf1 = *(const f16x8*)(W2th + (size_t)(1 * 16 + n0) * 2112 + e0f);

    // ---- 2-deep pipelined gather: v_stg = pass p data (staged now),
    //      v_nxt = pass p+1 data (regs), v_pf = pass p+2 (issued in pass p)
    f16x8 v_stg[4], v_nxt[4];
    #pragma unroll
    for (int i = 0; i < 4; ++i)
        v_stg[i] = *(const f16x8*)(xlh + ((size_t)(0 + m_h) * 2048 + indr[i]) * 64 + m_oct * 8);
    #pragma unroll
    for (int i = 0; i < 4; ++i)
        v_nxt[i] = *(const f16x8*)(xlh + ((size_t)(2 + m_h) * 2048 + indr[i]) * 64 + m_oct * 8);
    #pragma unroll
    for (int jj = 0; jj < 8; ++jj) {
        f16x4 pk = {v_stg[0][jj], v_stg[1][jj], v_stg[2][jj], v_stg[3][jj]};
        *(f16x4*)(&Xg[m_base + 136 * jj]) = pk;
    }
    __syncthreads();

    const int cA = cq * 16 + n0;
    const int cswz = h * 8768 + cA * 136 + ((cA >> 3) << 3);

    #pragma unroll
    for (int p = 0; p < 4; ++p) {
        f16x8 v_pf[4];
        if (p < 2) {      // issue pass p+2 loads now (2 passes of cover)
            #pragma unroll
            for (int i = 0; i < 4; ++i)
                v_pf[i] = *(const f16x8*)(xlh + ((size_t)(2 * (p + 2) + m_h) * 2048 + indr[i]) * 64 + m_oct * 8);
        }
        f32x4 Dz[3];
        #pragma unroll
        for (int r = 0; r < 3; ++r) Dz[r] = (f32x4){0.f, 0.f, 0.f, 0.f};
        #pragma unroll
        for (int ks = 0; ks < 4; ++ks) {
            f16x8 bfr = *(const f16x8*)(&Xg[cswz + ks * 32 + quad * 8]);
            #pragma unroll
            for (int r = 0; r < 3; ++r)
                Dz[r] = __builtin_amdgcn_mfma_f32_16x16x32_f16(afr[ks][r], bfr, Dz[r], 0, 0, 0);
        }
        __syncthreads();          // Xg reads done
        const int bt = 2 * p + h;
        #pragma unroll
        for (int r = 0; r < 3; ++r)
            #pragma unroll
            for (int reg = 0; reg < 4; ++reg) {
                int j = r * 16 + quad * 4 + reg;     // (j>>2)&3 == quad
                if (j < 33) Zh8[bt * 2120 + j * 64 + (cA ^ (quad << 4))] = (_Float16)Dz[r][reg];
            }
        if (p < 3) {
            #pragma unroll
            for (int jj = 0; jj < 8; ++jj) {
                f16x4 pk = {v_nxt[0][jj], v_nxt[1][jj], v_nxt[2][jj], v_nxt[3][jj]};
                *(f16x4*)(&Xg[m_base + 136 * jj]) = pk;
            }
            __syncthreads();
            #pragma unroll
            for (int i = 0; i < 4; ++i) v_nxt[i] = v_pf[i];   // rotate regs
        }
    }
    __syncthreads();              // all Zh8 writes visible

    // ---- GEMM2: one M=8 pass, s == wid (mod 8), s in [0,66) ---------------
    // Zh8 phys col = logical ^ (((j>>2)&3)<<4), j = s>>1 (matches write side)
    f32x4 D2[2][2];
    #pragma unroll
    for (int pp = 0; pp < 2; ++pp)
        #pragma unroll
        for (int dt = 0; dt < 2; ++dt) D2[pp][dt] = (f32x4){0.f, 0.f, 0.f, 0.f};
    {
        const int s = wid;
        const int ja = s >> 1;
        const int phys = (((s & 1) << 5) + quad * 8) ^ (((s >> 3) & 3) << 4);
        f16x8 a2 = {0, 0, 0, 0, 0, 0, 0, 0};
        if (n0 < 8) a2 = *(const f16x8*)(&Zh8[n0 * 2120 + ja * 64 + phys]);
        D2[0][0] = __builtin_amdgcn_mfma_f32_16x16x32_f16(a2, pf0, D2[0][0], 0, 0, 0);
        D2[0][1] = __builtin_amdgcn_mfma_f32_16x16x32_f16(a2, pf1, D2[0][1], 0, 0, 0);
    }
    // software-pipelined: cur regs hold s-iteration fragments, prefetch s+8
    f16x8 c0, c1;
    {
        const int s1 = wid + 8;
        const int e1 = s1 * 32 + quad * 8;
        c0 = *(const f16x8*)(W2th + (size_t)(0 * 16 + n0) * 2112 + e1);
        c1 = *(const f16x8*)(W2th + (size_t)(1 * 16 + n0) * 2112 + e1);
    }
    int pp = 1;
    for (int s = wid + 8; s < 66; s += 8) {
        const int sn = s + 8;
        f16x8 nx0, nx1;
        if (sn < 66) {
            const int en = sn * 32 + quad * 8;
            nx0 = *(const f16x8*)(W2th + (size_t)(0 * 16 + n0) * 2112 + en);
            nx1 = *(const f16x8*)(W2th + (size_t)(1 * 16 + n0) * 2112 + en);
        }
        const int ja = s >> 1;
        const int phys = (((s & 1) << 5) + quad * 8) ^ (((s >> 3) & 3) << 4);
        f16x8 a2 = {0, 0, 0, 0, 0, 0, 0, 0};
        if (n0 < 8) a2 = *(const f16x8*)(&Zh8[n0 * 2120 + ja * 64 + phys]);
        D2[pp][0] = __builtin_amdgcn_mfma_f32_16x16x32_f16(a2, c0, D2[pp][0], 0, 0, 0);
        D2[pp][1] = __builtin_amdgcn_mfma_f32_16x16x32_f16(a2, c1, D2[pp][1], 0, 0, 0);
        c0 = nx0; c1 = nx1;
        pp ^= 1;
    }
    #pragma unroll
    for (int dt = 0; dt < 2; ++dt)
        D2[0][dt] = D2[0][dt] + D2[1][dt];

    // D rows: bt = quad*4 + reg -> quads 0,1 hold bt 0..7
    if (quad < 2) {
        #pragma unroll
        for (int dt = 0; dt < 2; ++dt)
            #pragma unroll
            for (int reg = 0; reg < 4; ++reg)
                red[((wid * 2 + dt) * 8 + quad * 4 + reg) * 16 + n0] = D2[0][dt][reg];
    }
    __syncthreads();
    if (tid < 256) {
        const int bt = tid >> 5;
        const int d = tid & 31;
        const int dt = d >> 4;
        const int dn = d & 15;
        float s = 0.0f;
        #pragma unroll
        for (int w2 = 0; w2 < 8; ++w2)
            s += red[((w2 * 2 + dt) * 8 + bt) * 16 + dn];
        out[((size_t)bt * 512 + q) * 32 + d] = bias[d] + it * s;
    }
}

// ---------------------------------------------------------------------------
extern "C" void kernel_launch(void* const* d_in, const int* in_sizes, int n_in,
                              void* d_out, int out_size, void* d_ws, size_t ws_size,
                              hipStream_t stream) {
    const float* x     = (const float*)d_in[0];   // (2,4,2048,64)
    const float* pos   = (const float*)d_in[1];   // (2048,2)
    const float* qpos  = (const float*)d_in[2];   // (512,2)
    const float* W_lin = (const float*)d_in[3];   // (64,64)
    const float* b_lin = (const float*)d_in[4];   // (64)
    const float* Bmat  = (const float*)d_in[5];   // (2,16)
    const float* W1    = (const float*)d_in[6];   // (32,32)
    const float* b1    = (const float*)d_in[7];   // (32)
    const float* W2    = (const float*)d_in[8];   // (2048,32)
    const float* filt  = (const float*)d_in[9];   // (2048)
    const float* bias  = (const float*)d_in[10];  // (32)
    float* out = (float*)d_out;

    float* ws = (float*)d_ws;
    _Float16* xlh    = (_Float16*)ws;               // 1048576 halfs
    _Float16* Hh     = (_Float16*)(ws + 524288);    // 512*6144 halfs
    int*      indg   = (int*)(ws + 2097152);        // 512*128 ints (padded)
    _Float16* W2th   = (_Float16*)(ws + 2162688);   // 32*2112 halfs
    float*    invtot = ws + 2196480;                // 512 floats

    k12<<<768, 512, 0, stream>>>(pos, qpos, Bmat, W1, b1, Hh, indg, invtot,
                                 x, W_lin, b_lin, xlh, W2, filt, W2th);
    k3_main<<<512, 512, 0, stream>>>(xlh, Hh, indg, W2th, bias, invtot, out);
}